// Round 5
// baseline (176.732 us; speedup 1.0000x reference)
//
#include <hip/hip_runtime.h>

// pixelSNAIL causal attention, MI355X gfx950.
// B=32, N=1024, C=128, CM=256, fp32 in/out.
// softmax over FULL row, strict causal mask, then @V.
// R5 = R4 resubmit (R4 bench died to container infra, no counters).
// Wave owns 32 q-rows (2 A-frags) -> K LDS reads amortized 2x; V read
// straight from frag-ordered ws into registers (no LDS); stripe pairing
// (p, 15-p) makes PV work uniform across blocks; CM split keeps VGPR <= 256.
// K double-buffered gl2lds with partial vmcnt + raw s_barrier (AITER style).

typedef __attribute__((ext_vector_type(8))) short short8;
typedef __attribute__((ext_vector_type(4))) float floatx4;

#define MFMA16(a, b, c) __builtin_amdgcn_mfma_f32_16x16x32_bf16((a), (b), (c), 0, 0, 0)

constexpr int N = 1024, C = 128, CM = 256, BATCH = 32;
constexpr int BN = 32;             // keys per tile
constexpr int NT = N / BN;         // 32 tiles
constexpr int KFRAG = BN * C;      // 4096 bf16 per K tile (hi or lo)
constexpr int VFRAG = BN * CM;     // 8192 bf16 per V tile
constexpr int PSTR = 40;           // P LDS row stride (bf16)

__device__ __forceinline__ unsigned short f2bf(float x) {
    unsigned int u = __float_as_uint(x);
    u += 0x7fffu + ((u >> 16) & 1u);   // RNE
    return (unsigned short)(u >> 16);
}
__device__ __forceinline__ float bf2f(unsigned short h) {
    return __uint_as_float(((unsigned int)h) << 16);
}
__device__ __forceinline__ uint4 pack8(const unsigned short* s) {
    uint4 u;
    u.x = (unsigned)s[0] | ((unsigned)s[1] << 16);
    u.y = (unsigned)s[2] | ((unsigned)s[3] << 16);
    u.z = (unsigned)s[4] | ((unsigned)s[5] << 16);
    u.w = (unsigned)s[6] | ((unsigned)s[7] << 16);
    return u;
}
__device__ __forceinline__ void gl2lds16(const unsigned short* g, unsigned short* l) {
    __builtin_amdgcn_global_load_lds(
        (const __attribute__((address_space(1))) void*)g,
        (__attribute__((address_space(3))) void*)l, 16, 0, 0);
}

// ---------------- prepass: no LDS, no barriers ----------------
// Khi/Klo frag order per tile: chunk ch = (t*4+ks)*64 + ln, elem j:
//   K[key = tile*32 + t*16 + (ch&15)][c = ks*32 + ((ch>>4)&3)*8 + j]
// V frag order per tile: chunk ch = ct*64 + ln, elem j:
//   V[key = tile*32 + ((ch>>4)&3)*8 + j][cm = ct*16 + (ch&15)]
__global__ __launch_bounds__(256, 8)
void prep_kernel(const float* __restrict__ kg, const float* __restrict__ vg,
                 unsigned short* __restrict__ khi, unsigned short* __restrict__ klo,
                 unsigned short* __restrict__ vf)
{
    const int tid = threadIdx.x;
    const int tile = blockIdx.x, bat = blockIdx.y;
    const int n0 = tile * BN;
    const float* kb = kg + (size_t)bat * N * C;
    const float* vb = vg + (size_t)bat * N * CM;
    unsigned short* khb = khi + ((size_t)bat * NT + tile) * KFRAG;
    unsigned short* klb = klo + ((size_t)bat * NT + tile) * KFRAG;
    unsigned short* vfb = vf + ((size_t)bat * NT + tile) * VFRAG;

#pragma unroll
    for (int i = 0; i < 2; ++i) {
        int ch = tid + i * 256;
        int r = ch & 15, qd = (ch >> 4) & 3, ks = (ch >> 6) & 3, t = ch >> 8;
        const float* src = kb + (size_t)(n0 + t * 16 + r) * C + ks * 32 + qd * 8;
        float4 a = *(const float4*)src;
        float4 b = *(const float4*)(src + 4);
        float xs[8] = {a.x, a.y, a.z, a.w, b.x, b.y, b.z, b.w};
        unsigned short hi[8], lo[8];
#pragma unroll
        for (int j = 0; j < 8; ++j) {
            unsigned short h = f2bf(xs[j]);
            hi[j] = h;
            lo[j] = f2bf(xs[j] - bf2f(h));
        }
        *(uint4*)(khb + (size_t)ch * 8) = pack8(hi);
        *(uint4*)(klb + (size_t)ch * 8) = pack8(lo);
    }
#pragma unroll
    for (int i = 0; i < 4; ++i) {
        int ch = tid + i * 256;
        int r = ch & 15, qd = (ch >> 4) & 3, ct = ch >> 6;
        const float* src = vb + (size_t)(n0 + qd * 8) * CM + ct * 16 + r;
        unsigned short o[8];
#pragma unroll
        for (int j = 0; j < 8; ++j)
            o[j] = f2bf(src[(size_t)j * CM]);
        *(uint4*)(vfb + (size_t)ch * 8) = pack8(o);
    }
}

// ---------------- main attention kernel ----------------
__global__ __launch_bounds__(256, 2)
void attn_kernel(const float* __restrict__ qg, float* __restrict__ og,
                 const unsigned short* __restrict__ khi,
                 const unsigned short* __restrict__ klo,
                 const unsigned short* __restrict__ vf)
{
    __shared__ __align__(16) unsigned short sKhi[2][KFRAG];    // 16 KB dbuf
    __shared__ __align__(16) unsigned short sKlo[2][KFRAG];    // 16 KB dbuf
    __shared__ __align__(16) unsigned short sP[8 * 16 * PSTR]; // 10 KB

    const int tid = threadIdx.x;
    const int w = tid >> 6, ln = tid & 63;
    const int r = ln & 15, qd = ln >> 4;
    const int bat = blockIdx.x;    // whole batch's blocks hit the same XCD L2 set
    const int pair = blockIdx.y;   // 0..7
    const int half = blockIdx.z;   // CM half
    const int sa = pair, sb = 15 - pair;   // paired 64-row stripes: uniform PV work

    const float* qb = qg + (size_t)bat * N * C;
    float* ob = og + (size_t)bat * N * CM;
    const unsigned short* khb = khi + (size_t)bat * NT * KFRAG;
    const unsigned short* klb = klo + (size_t)bat * NT * KFRAG;
    const unsigned short* vfb = vf + (size_t)bat * NT * VFRAG;

    // ---- Q fragments for both stripes (rows s*64 + w*16 + r), hi/lo split ----
    short8 qAh[4], qAl[4], qBh[4], qBl[4];
#pragma unroll
    for (int f = 0; f < 2; ++f) {
        const int row = (f ? sb : sa) * 64 + w * 16 + r;
        const float* qr = qb + (size_t)row * C + qd * 8;
#pragma unroll
        for (int ks = 0; ks < 4; ++ks) {
            float4 a = *(const float4*)(qr + ks * 32);
            float4 b = *(const float4*)(qr + ks * 32 + 4);
            float xs[8] = {a.x, a.y, a.z, a.w, b.x, b.y, b.z, b.w};
            short8 h, l;
#pragma unroll
            for (int j = 0; j < 8; ++j) {
                unsigned short hb = f2bf(xs[j]);
                h[j] = (short)hb;
                l[j] = (short)f2bf(xs[j] - bf2f(hb));
            }
            if (f) { qBh[ks] = h; qBl[ks] = l; }
            else   { qAh[ks] = h; qAl[ks] = l; }
        }
    }

    floatx4 oaccA[8], oaccB[8];
#pragma unroll
    for (int ct = 0; ct < 8; ++ct) {
        oaccA[ct] = (floatx4){0.f, 0.f, 0.f, 0.f};
        oaccB[ct] = (floatx4){0.f, 0.f, 0.f, 0.f};
    }
    float lsA[4] = {0.f, 0.f, 0.f, 0.f};
    float lsB[4] = {0.f, 0.f, 0.f, 0.f};
    const int irA = sa * 64 + w * 16 + qd * 4;
    const int irB = sb * 64 + w * 16 + qd * 4;
    unsigned short* wPA = &sP[(w * 2 + 0) * 16 * PSTR];
    unsigned short* wPB = &sP[(w * 2 + 1) * 16 * PSTR];

    // prologue: stage K tile 0 into buffer 0 (4 gl2lds / thread)
    gl2lds16(khb + (size_t)tid * 8,         &sKhi[0][tid * 8]);
    gl2lds16(khb + (size_t)(tid + 256) * 8, &sKhi[0][(tid + 256) * 8]);
    gl2lds16(klb + (size_t)tid * 8,         &sKlo[0][tid * 8]);
    gl2lds16(klb + (size_t)(tid + 256) * 8, &sKlo[0][(tid + 256) * 8]);

    for (int tile = 0; tile < NT; ++tile) {
        const int cb = tile & 1;
        const bool pvA = (tile <= 2 * sa + 1);   // block-uniform; pvA => pvB
        const bool pvB = (tile <= 2 * sb + 1);

        // ---- V(t) B-frags straight into registers (no LDS), CM half ----
        short8 vr[8];
        if (pvB) {
            const unsigned short* vs = vfb + (size_t)tile * VFRAG;
#pragma unroll
            for (int ct = 0; ct < 8; ++ct)
                vr[ct] = *(const short8*)(vs + (size_t)(((half * 8 + ct) * 64) + ln) * 8);
        }
        // ---- stage K(t+1) into other buffer; stays in flight across barrier ----
        if (tile + 1 < NT) {
            const unsigned short* k1 = khb + (size_t)(tile + 1) * KFRAG;
            const unsigned short* l1 = klb + (size_t)(tile + 1) * KFRAG;
            unsigned short* dh = &sKhi[cb ^ 1][0];
            unsigned short* dl = &sKlo[cb ^ 1][0];
            gl2lds16(k1 + (size_t)tid * 8,         dh + tid * 8);
            gl2lds16(k1 + (size_t)(tid + 256) * 8, dh + (tid + 256) * 8);
            gl2lds16(l1 + (size_t)tid * 8,         dl + tid * 8);
            gl2lds16(l1 + (size_t)(tid + 256) * 8, dl + (tid + 256) * 8);
            // drain K(t) (oldest 4); leave vr + K(t+1) in flight
            if (pvB) asm volatile("s_waitcnt vmcnt(12)" ::: "memory");
            else     asm volatile("s_waitcnt vmcnt(4)" ::: "memory");
        } else {
            asm volatile("s_waitcnt vmcnt(0)" ::: "memory");
        }
        asm volatile("s_barrier" ::: "memory");

        // ---- QK^T bf16x3 for both frags: 6 independent chains ----
#pragma unroll
        for (int t = 0; t < 2; ++t) {
            floatx4 aA0 = (floatx4){0.f,0.f,0.f,0.f}, aA1 = aA0, aA2 = aA0;
            floatx4 aB0 = aA0, aB1 = aA0, aB2 = aA0;
#pragma unroll
            for (int ks = 0; ks < 4; ++ks) {
                short8 bh = *(const short8*)(&sKhi[cb][(((t * 4 + ks) * 64) + ln) * 8]);
                short8 bl = *(const short8*)(&sKlo[cb][(((t * 4 + ks) * 64) + ln) * 8]);
                aA0 = MFMA16(qAh[ks], bh, aA0);
                aA1 = MFMA16(qAl[ks], bh, aA1);
                aA2 = MFMA16(qAh[ks], bl, aA2);
                aB0 = MFMA16(qBh[ks], bh, aB0);
                aB1 = MFMA16(qBl[ks], bh, aB1);
                aB2 = MFMA16(qBh[ks], bl, aB2);
            }
            const int jg = tile * BN + t * 16 + r;
#pragma unroll
            for (int rg = 0; rg < 4; ++rg) {
                float pA = __expf(aA0[rg] + aA1[rg] + aA2[rg] - 40.0f);
                float pB = __expf(aB0[rg] + aB1[rg] + aB2[rg] - 40.0f);
                lsA[rg] += pA;                       // full-row denominators
                lsB[rg] += pB;
                if (pvA)
                    wPA[(qd * 4 + rg) * PSTR + t * 16 + r] = f2bf((jg < irA + rg) ? pA : 0.0f);
                if (pvB)
                    wPB[(qd * 4 + rg) * PSTR + t * 16 + r] = f2bf((jg < irB + rg) ? pB : 0.0f);
            }
        }

        // ---- PV: wave-private P round-trip, V from registers ----
        if (pvB) {
            asm volatile("s_waitcnt lgkmcnt(0)" ::: "memory");
            short8 apB = *(const short8*)(&wPB[r * PSTR + qd * 8]);
#pragma unroll
            for (int ct = 0; ct < 8; ++ct)
                oaccB[ct] = MFMA16(apB, vr[ct], oaccB[ct]);
            if (pvA) {
                short8 apA = *(const short8*)(&wPA[r * PSTR + qd * 8]);
#pragma unroll
                for (int ct = 0; ct < 8; ++ct)
                    oaccA[ct] = MFMA16(apA, vr[ct], oaccA[ct]);
            }
        }
        asm volatile("s_barrier" ::: "memory");   // K[cb] readers done before overwrite
    }

    // ---- denominators: reduce across the 16 key-lanes ----
#pragma unroll
    for (int rg = 0; rg < 4; ++rg) {
        float a = lsA[rg], b = lsB[rg];
        a += __shfl_xor(a, 1); b += __shfl_xor(b, 1);
        a += __shfl_xor(a, 2); b += __shfl_xor(b, 2);
        a += __shfl_xor(a, 4); b += __shfl_xor(b, 4);
        a += __shfl_xor(a, 8); b += __shfl_xor(b, 8);
        lsA[rg] = a; lsB[rg] = b;
    }

    // ---- divide + store (CM half) ----
#pragma unroll
    for (int rg = 0; rg < 4; ++rg) {
        float invA = 1.0f / lsA[rg];
        float invB = 1.0f / lsB[rg];
        float* oA = ob + (size_t)(irA + rg) * CM + half * 128;
        float* oB = ob + (size_t)(irB + rg) * CM + half * 128;
#pragma unroll
        for (int ct = 0; ct < 8; ++ct) {
            oA[ct * 16 + r] = oaccA[ct][rg] * invA;
            oB[ct * 16 + r] = oaccB[ct][rg] * invB;
        }
    }
}

extern "C" void kernel_launch(void* const* d_in, const int* in_sizes, int n_in,
                              void* d_out, int out_size, void* d_ws, size_t ws_size,
                              hipStream_t stream) {
    const float* q = (const float*)d_in[0];
    const float* k = (const float*)d_in[1];
    const float* v = (const float*)d_in[2];
    float* o = (float*)d_out;
    (void)n_in; (void)in_sizes; (void)out_size; (void)ws_size;

    unsigned short* khi = (unsigned short*)d_ws;                       // 8 MB
    unsigned short* klo = khi + (size_t)BATCH * NT * KFRAG;            // 8 MB
    unsigned short* vf  = klo + (size_t)BATCH * NT * KFRAG;            // 16 MB

    prep_kernel<<<dim3(NT, BATCH), dim3(256), 0, stream>>>(k, v, khi, klo, vf);
    attn_kernel<<<dim3(BATCH, 8, 2), dim3(256), 0, stream>>>(q, o, khi, klo, vf);
}

// Round 6
// 162.938 us; speedup vs baseline: 1.0847x; 1.0847x over previous
//
#include <hip/hip_runtime.h>

// pixelSNAIL causal attention, MI355X gfx950.
// B=32, N=1024, C=128, CM=256, fp32 in/out.
// softmax over FULL row, strict causal mask, then @V.
// R6: fp16 Q/K single-MFMA QK (1/3 the QK MFMAs, 1/2 the K LDS bytes of
// bf16x3; logit err ~0.005 std, safe vs 0.1 threshold). 128-thr blocks,
// wave owns 32 rows (2 A-frags, stripes p and 31-p -> uniform pv load),
// each K/V b128 read feeds 2 MFMAs. LDS 37.9KB -> 4 blocks/CU. K dbuf
// gl2lds pipeline w/ partial vmcnt + raw s_barrier (proven in R3).
// Prep: coalesced V transpose via LDS (fixes 1KB-strided scalar reads).

typedef __attribute__((ext_vector_type(8))) _Float16 half8;
typedef __attribute__((ext_vector_type(8))) short short8;
typedef __attribute__((ext_vector_type(4))) float floatx4;

#define MFMA_F16(a, b, c)  __builtin_amdgcn_mfma_f32_16x16x32_f16((a), (b), (c), 0, 0, 0)
#define MFMA_BF16(a, b, c) __builtin_amdgcn_mfma_f32_16x16x32_bf16((a), (b), (c), 0, 0, 0)

constexpr int N = 1024, C = 128, CM = 256, BATCH = 32;
constexpr int BN = 32;             // keys per tile
constexpr int NT = N / BN;         // 32 tiles
constexpr int KFRAG = BN * C;      // 4096 fp16 per K tile (8 KB)
constexpr int VFRAG = BN * CM;     // 8192 bf16 per V tile (16 KB)
constexpr int PSTR = 40;           // P LDS row stride (bf16); 80 B rows (16B-aligned)

__device__ __forceinline__ unsigned short f2bf(float x) {
    unsigned int u = __float_as_uint(x);
    u += 0x7fffu + ((u >> 16) & 1u);   // RNE
    return (unsigned short)(u >> 16);
}
__device__ __forceinline__ uint4 pack8(const unsigned short* s) {
    uint4 u;
    u.x = (unsigned)s[0] | ((unsigned)s[1] << 16);
    u.y = (unsigned)s[2] | ((unsigned)s[3] << 16);
    u.z = (unsigned)s[4] | ((unsigned)s[5] << 16);
    u.w = (unsigned)s[6] | ((unsigned)s[7] << 16);
    return u;
}
__device__ __forceinline__ void gl2lds16(const void* g, void* l) {
    __builtin_amdgcn_global_load_lds(
        (const __attribute__((address_space(1))) void*)g,
        (__attribute__((address_space(3))) void*)l, 16, 0, 0);
}

// ---------------- prepass: K -> fp16 frags (direct), V -> bf16 frags (LDS transpose) ----
// K frag order per tile: chunk ch = (t*4+ks)*64 + ln, elem j:
//   K[key = tile*32 + t*16 + (ch&15)][c = ks*32 + ((ch>>4)&3)*8 + j]
// V frag order per tile: chunk ch = ct*64 + ln, elem j:
//   V[key = tile*32 + ((ch>>4)&3)*8 + j][cm = ct*16 + (ch&15)]
__global__ __launch_bounds__(256, 2)
void prep_kernel(const float* __restrict__ kg, const float* __restrict__ vg,
                 _Float16* __restrict__ kf, unsigned short* __restrict__ vf)
{
    constexpr int VP = 260;   // fp32 LDS stride for V rows (+4 pad)
    __shared__ __align__(16) float S[BN * VP];   // 33280 B

    const int tid = threadIdx.x;
    const int tile = blockIdx.x, bat = blockIdx.y;
    const int n0 = tile * BN;
    const float* kb = kg + (size_t)bat * N * C;
    const float* vb = vg + (size_t)bat * N * CM;
    _Float16* kfb = kf + ((size_t)bat * NT + tile) * KFRAG;
    unsigned short* vfb = vf + ((size_t)bat * NT + tile) * VFRAG;

    // K: 512 chunks, 2/thread, 32B contiguous per lane (L1-friendly)
#pragma unroll
    for (int i = 0; i < 2; ++i) {
        int ch = tid + i * 256;
        int r = ch & 15, qd = (ch >> 4) & 3, ks = (ch >> 6) & 3, t = ch >> 8;
        const float* src = kb + (size_t)(n0 + t * 16 + r) * C + ks * 32 + qd * 8;
        float4 a = *(const float4*)src;
        float4 b = *(const float4*)(src + 4);
        half8 h = { (_Float16)a.x, (_Float16)a.y, (_Float16)a.z, (_Float16)a.w,
                    (_Float16)b.x, (_Float16)b.y, (_Float16)b.z, (_Float16)b.w };
        *(half8*)(kfb + (size_t)ch * 8) = h;
    }

    // V: coalesced float4 loads -> LDS, then strided gather (LDS is fast) -> frags
#pragma unroll
    for (int i = 0; i < 8; ++i) {
        int f = tid + i * 256;              // 2048 float4
        int row = f >> 6, c4 = f & 63;
        float4 x = *(const float4*)(vb + (size_t)(n0 + row) * CM + c4 * 4);
        *(float4*)(&S[row * VP + c4 * 4]) = x;
    }
    __syncthreads();
#pragma unroll
    for (int i = 0; i < 4; ++i) {
        int ch = tid + i * 256;             // 1024 chunks
        int r = ch & 15, qd = (ch >> 4) & 3, ct = ch >> 6;
        unsigned short o[8];
#pragma unroll
        for (int j = 0; j < 8; ++j)
            o[j] = f2bf(S[(qd * 8 + j) * VP + ct * 16 + r]);
        *(uint4*)(vfb + (size_t)ch * 8) = pack8(o);
    }
}

// ---------------- main attention kernel: 128 threads / 2 waves ----------------
__global__ __launch_bounds__(128, 2)
void attn_kernel(const float* __restrict__ qg, float* __restrict__ og,
                 const _Float16* __restrict__ kf,
                 const unsigned short* __restrict__ vf)
{
    __shared__ __align__(16) _Float16 sK[2][KFRAG];            // 16 KB dbuf
    __shared__ __align__(16) unsigned short sV[VFRAG];         // 16 KB
    __shared__ __align__(16) unsigned short sP[4 * 16 * PSTR]; // 5 KB (2 waves x 2 frags)

    const int tid = threadIdx.x;
    const int w = tid >> 6, ln = tid & 63;
    const int r = ln & 15, qd = ln >> 4;
    const int bat = blockIdx.x;     // whole batch's blocks share XCD L2
    const int p = blockIdx.y;       // 0..15
    const int sa = p, sb = 31 - p;  // paired 32-row stripes; sb > sa always

    const float* qb = qg + (size_t)bat * N * C;
    float* ob = og + (size_t)bat * N * CM;
    const _Float16* kfb = kf + (size_t)bat * NT * KFRAG;
    const unsigned short* vfb = vf + (size_t)bat * NT * VFRAG;

    // ---- Q fragments fp16 for both stripes (rows s*32 + w*16 + r) ----
    half8 qA[4], qB[4];
#pragma unroll
    for (int f = 0; f < 2; ++f) {
        const int row = (f ? sb : sa) * 32 + w * 16 + r;
        const float* qr = qb + (size_t)row * C + qd * 8;
#pragma unroll
        for (int ks = 0; ks < 4; ++ks) {
            float4 a = *(const float4*)(qr + ks * 32);
            float4 b = *(const float4*)(qr + ks * 32 + 4);
            half8 h = { (_Float16)a.x, (_Float16)a.y, (_Float16)a.z, (_Float16)a.w,
                        (_Float16)b.x, (_Float16)b.y, (_Float16)b.z, (_Float16)b.w };
            if (f) qB[ks] = h; else qA[ks] = h;
        }
    }

    floatx4 oA[16], oB[16];
#pragma unroll
    for (int ct = 0; ct < 16; ++ct) {
        oA[ct] = (floatx4){0.f, 0.f, 0.f, 0.f};
        oB[ct] = (floatx4){0.f, 0.f, 0.f, 0.f};
    }
    float lsA[4] = {0.f, 0.f, 0.f, 0.f};
    float lsB[4] = {0.f, 0.f, 0.f, 0.f};
    const int irA = sa * 32 + w * 16 + qd * 4;
    const int irB = sb * 32 + w * 16 + qd * 4;
    unsigned short* wPA = &sP[(w * 2 + 0) * 16 * PSTR];
    unsigned short* wPB = &sP[(w * 2 + 1) * 16 * PSTR];

    // prologue: stage K tile 0 into buffer 0 (4 gl2lds / thread, 128 thr)
#pragma unroll
    for (int i = 0; i < 4; ++i) {
        int idx = tid + i * 128;
        gl2lds16(kfb + (size_t)idx * 8, &sK[0][idx * 8]);
    }

    for (int tile = 0; tile < NT; ++tile) {
        const int cb = tile & 1;
        const bool pvA = (tile <= sa);   // block-uniform; pvA implies pvB
        const bool pvB = (tile <= sb);

        // ---- stage V(t) (single-buffered; prior readers cleared by tail barrier) ----
        if (pvB) {
            const unsigned short* vs = vfb + (size_t)tile * VFRAG;
#pragma unroll
            for (int i = 0; i < 8; ++i) {
                int idx = tid + i * 128;
                gl2lds16(vs + (size_t)idx * 8, &sV[idx * 8]);
            }
        }
        // ---- stage K(t+1) into the other buffer; stays in flight across barrier ----
        if (tile + 1 < NT) {
            const _Float16* k1 = kfb + (size_t)(tile + 1) * KFRAG;
            _Float16* dk = &sK[cb ^ 1][0];
#pragma unroll
            for (int i = 0; i < 4; ++i) {
                int idx = tid + i * 128;
                gl2lds16(k1 + (size_t)idx * 8, dk + idx * 8);
            }
            // drain K(t) [+ V(t) if issued]; leave the 4 K(t+1) loads in flight
            asm volatile("s_waitcnt vmcnt(4)" ::: "memory");
        } else {
            asm volatile("s_waitcnt vmcnt(0)" ::: "memory");
        }
        asm volatile("s_barrier" ::: "memory");

        // ---- QK^T fp16, 2 frags share each B read: 8 reads -> 16 MFMAs ----
#pragma unroll
        for (int t = 0; t < 2; ++t) {
            floatx4 aA = (floatx4){0.f, 0.f, 0.f, 0.f};
            floatx4 aB = (floatx4){0.f, 0.f, 0.f, 0.f};
#pragma unroll
            for (int ks = 0; ks < 4; ++ks) {
                half8 bh = *(const half8*)(&sK[cb][(((t * 4 + ks) * 64) + ln) * 8]);
                aA = MFMA_F16(qA[ks], bh, aA);
                aB = MFMA_F16(qB[ks], bh, aB);
            }
            const int jg = tile * BN + t * 16 + r;
#pragma unroll
            for (int rg = 0; rg < 4; ++rg) {
                float pA = __expf(aA[rg] - 40.0f);
                float pB = __expf(aB[rg] - 40.0f);
                lsA[rg] += pA;                       // full-row denominators (unmasked)
                lsB[rg] += pB;
                if (pvA)
                    wPA[(qd * 4 + rg) * PSTR + t * 16 + r] = f2bf((jg < irA + rg) ? pA : 0.0f);
                if (pvB)
                    wPB[(qd * 4 + rg) * PSTR + t * 16 + r] = f2bf((jg < irB + rg) ? pB : 0.0f);
            }
        }

        // ---- PV: each V b128 read feeds both row-frags ----
        if (pvB) {
            asm volatile("s_waitcnt lgkmcnt(0)" ::: "memory");  // wP writes landed (same wave)
            short8 apB = *(const short8*)(&wPB[r * PSTR + qd * 8]);
            short8 apA;
            if (pvA) apA = *(const short8*)(&wPA[r * PSTR + qd * 8]);
#pragma unroll
            for (int ct = 0; ct < 16; ++ct) {
                short8 bv = *(const short8*)(&sV[(ct * 64 + ln) * 8]);
                oB[ct] = MFMA_BF16(apB, bv, oB[ct]);
                if (pvA) oA[ct] = MFMA_BF16(apA, bv, oA[ct]);
            }
        }
        asm volatile("s_barrier" ::: "memory");   // readers done before next overwrite
    }

    // ---- denominators: reduce across the 16 key-lanes ----
#pragma unroll
    for (int rg = 0; rg < 4; ++rg) {
        float a = lsA[rg], b = lsB[rg];
        a += __shfl_xor(a, 1); b += __shfl_xor(b, 1);
        a += __shfl_xor(a, 2); b += __shfl_xor(b, 2);
        a += __shfl_xor(a, 4); b += __shfl_xor(b, 4);
        a += __shfl_xor(a, 8); b += __shfl_xor(b, 8);
        lsA[rg] = a; lsB[rg] = b;
    }

    // ---- divide + store (full CM per row) ----
#pragma unroll
    for (int rg = 0; rg < 4; ++rg) {
        float invA = 1.0f / lsA[rg];
        float invB = 1.0f / lsB[rg];
        float* orA = ob + (size_t)(irA + rg) * CM;
        float* orB = ob + (size_t)(irB + rg) * CM;
#pragma unroll
        for (int ct = 0; ct < 16; ++ct) {
            orA[ct * 16 + r] = oA[ct][rg] * invA;
            orB[ct * 16 + r] = oB[ct][rg] * invB;
        }
    }
}

extern "C" void kernel_launch(void* const* d_in, const int* in_sizes, int n_in,
                              void* d_out, int out_size, void* d_ws, size_t ws_size,
                              hipStream_t stream) {
    const float* q = (const float*)d_in[0];
    const float* k = (const float*)d_in[1];
    const float* v = (const float*)d_in[2];
    float* o = (float*)d_out;
    (void)n_in; (void)in_sizes; (void)out_size; (void)ws_size;

    _Float16* kfrag = (_Float16*)d_ws;                                   // 8 MB
    unsigned short* vfrag = (unsigned short*)(kfrag + (size_t)BATCH * NT * KFRAG); // 16 MB

    prep_kernel<<<dim3(NT, BATCH), dim3(256), 0, stream>>>(k, v, kfrag, vfrag);
    attn_kernel<<<dim3(BATCH, 16), dim3(128), 0, stream>>>(q, o, kfrag, vfrag);
}